// Round 12
// baseline (436.841 us; speedup 1.0000x reference)
//
#include <hip/hip_runtime.h>

#define T_STEPS 500
#define BATCH   128
#define NINPUT  6
#define NH      500
#define THRV    1.0f
#define BETAV   0.5f
#define W2T_STRIDE 512
#define CSTRIDE 512    // cur2seg row stride (padded)
#define NGC     8      // s2 mask words per (t,b)
#define JC      256    // j-chunk width in cur2
#define KT      128    // W2 rows per LDS tile
#define SW      32     // scan2 LDS window (timesteps)

typedef unsigned long long ull;

static __device__ __forceinline__ ull rfl64(ull v) {
  unsigned lo = __builtin_amdgcn_readfirstlane((unsigned)v);
  unsigned hi = __builtin_amdgcn_readfirstlane((unsigned)(v >> 32));
  return ((ull)hi << 32) | lo;
}

// ---------------------------------------------------------------------------
// Transpose W2 [500][500] -> W2T [500][512] (padded stride, pad zeroed).
// ---------------------------------------------------------------------------
__global__ void transpose_w2(const float* __restrict__ W2, float* __restrict__ W2T) {
  int idx = blockIdx.x * 256 + threadIdx.x;
  if (idx < NH * W2T_STRIDE) {
    int i = idx >> 9;
    int j = idx & 511;
    W2T[idx] = (j < NH) ? W2[j * NH + i] : 0.f;
  }
}

// ---------------------------------------------------------------------------
// s1_seg: layer-1 LIF for t in [t0, t0+tc). grid = (128 b, 2 half), 256 thr.
// x slice staged in LDS; 4-deep statically-indexed prefetch ring, x4 unroll.
// half owns neurons [256*half, +256); wave w word = half*4+w.
// ---------------------------------------------------------------------------
__global__ __launch_bounds__(256) void s1_seg_kernel(
    const float* __restrict__ x,      // [T][B][6]
    const float* __restrict__ W1,     // [500][6]
    const float* __restrict__ b1,     // [500]
    float* __restrict__ m1state,      // [B][512]
    ull* __restrict__ s1seg,          // [tc][B][8]
    int t0, int tc)
{
  __shared__ float xs[T_STEPS * NINPUT];
  const int b = blockIdx.x, half = blockIdx.y;
  const int wid = threadIdx.x >> 6, lane = threadIdx.x & 63;

  for (int idx = threadIdx.x; idx < tc * NINPUT; idx += 256) {
    int h = idx / NINPUT, k = idx - h * NINPUT;
    xs[idx] = x[(size_t)((t0 + h) * BATCH + b) * NINPUT + k];
  }

  const int n = half * 256 + (wid << 6) + lane;
  const bool nv = (n < NH);
  const int word = half * 4 + wid;
  float w[6], b1v;
  #pragma unroll
  for (int k = 0; k < 6; ++k) w[k] = nv ? W1[n * NINPUT + k] : 0.f;
  b1v = nv ? b1[n] : 0.f;
  float m1 = (t0 == 0) ? 0.f : m1state[b * 512 + n];

  __syncthreads();

  #define LOADL(hh, xr) do {                                   \
    const float* p_ = xs + (hh) * NINPUT;                      \
    float2 a_ = *(const float2*)p_;                            \
    float2 c_ = *(const float2*)(p_ + 2);                      \
    float2 d_ = *(const float2*)(p_ + 4);                      \
    xr[0]=a_.x; xr[1]=a_.y; xr[2]=c_.x;                        \
    xr[3]=c_.y; xr[4]=d_.x; xr[5]=d_.y;                        \
  } while (0)

  float X[4][6];
  {
    int c1 = (tc > 1) ? 1 : 0, c2 = (tc > 2) ? 2 : 0, c3 = (tc > 3) ? 3 : 0;
    LOADL(0, X[0]); LOADL(c1, X[1]); LOADL(c2, X[2]); LOADL(c3, X[3]);
  }

  for (int h = 0; h < tc; h += 4) {
    #pragma unroll
    for (int u = 0; u < 4; ++u) {
      int hh = h + u;
      if (hh < tc) {
        float cur = b1v + w[0]*X[u][0] + w[1]*X[u][1] + w[2]*X[u][2]
                        + w[3]*X[u][3] + w[4]*X[u][4] + w[5]*X[u][5];
        float rst = (m1 > THRV) ? THRV : 0.f;
        m1 = BETAV * m1 + cur - rst;
        ull bm = __ballot((m1 > THRV) && nv);
        if (lane == 0) s1seg[((size_t)hh * BATCH + b) * 8 + word] = bm;
        int hp = hh + 4; if (hp > tc - 1) hp = tc - 1;
        LOADL(hp, X[u]);   // refill slot 4 steps ahead
      }
    }
  }
  #undef LOADL
  m1state[b * 512 + n] = m1;
}

// ---------------------------------------------------------------------------
// cur2_seg: cur2[h][b][j] = b2[j] + sum_{i active} W2[j][i].
// grid = (128 b, 2 jc), 1024 thr = 16 waves (4/SIMD), 1 block/CU (128 KB LDS).
// 4-wide peel + per-(r,kt) mask prefetch -> deep ds_read_b128 pipelining.
// Output stride padded to 512 (pad lanes write zeros).
// ---------------------------------------------------------------------------
#define PEEL4(mm, roff, A) do {                                               \
  ull m_ = (mm);                                                              \
  while (m_) {                                                                \
    int i0 = __builtin_ctzll(m_); m_ &= m_ - 1;                               \
    bool v1 = (m_ != 0); int i1 = v1 ? __builtin_ctzll(m_) : i0;              \
    if (v1) m_ &= m_ - 1;                                                     \
    bool v2 = (m_ != 0); int i2 = v2 ? __builtin_ctzll(m_) : i0;              \
    if (v2) m_ &= m_ - 1;                                                     \
    bool v3 = (m_ != 0); int i3 = v3 ? __builtin_ctzll(m_) : i0;              \
    if (v3) m_ &= m_ - 1;                                                     \
    float4 w0_ = W2L[(((roff) + i0) << 6) + lane];                            \
    float4 w1_ = W2L[(((roff) + i1) << 6) + lane];                            \
    float4 w2_ = W2L[(((roff) + i2) << 6) + lane];                            \
    float4 w3_ = W2L[(((roff) + i3) << 6) + lane];                            \
    A.x += w0_.x; A.y += w0_.y; A.z += w0_.z; A.w += w0_.w;                   \
    if (v1) { A.x += w1_.x; A.y += w1_.y; A.z += w1_.z; A.w += w1_.w; }       \
    if (v2) { A.x += w2_.x; A.y += w2_.y; A.z += w2_.z; A.w += w2_.w; }       \
    if (v3) { A.x += w3_.x; A.y += w3_.y; A.z += w3_.z; A.w += w3_.w; }       \
  }                                                                           \
} while (0)

__global__ __launch_bounds__(1024, 4) void cur2_seg_kernel(
    const ull* __restrict__ s1seg,    // [tc][B][8]
    const float* __restrict__ W2T,    // [500][512]
    const float* __restrict__ b2,     // [500]
    float* __restrict__ cur2seg,      // [tc][B][512]
    int tc)
{
  __shared__ float4 W2L[KT * (JC / 4)];   // 128 KB
  const int b = blockIdx.x, jc = blockIdx.y;
  const int tid = threadIdx.x;
  const int lane = tid & 63, wid = tid >> 6;   // wid 0..15
  const int j0 = jc * JC + (lane << 2);
  const bool jv = (j0 < NH);

  float4 b2v = make_float4(0.f, 0.f, 0.f, 0.f);
  if (jv) b2v = *(const float4*)(b2 + j0);

  for (int r = 0; r < 4; ++r) {
    float4 acc[8];
    #pragma unroll
    for (int g = 0; g < 8; ++g) acc[g] = make_float4(0.f, 0.f, 0.f, 0.f);

    for (int kt = 0; kt < 4; ++kt) {
      __syncthreads();
      for (int idx = tid; idx < KT * (JC / 4); idx += 1024) {
        int rr = idx >> 6, cc = idx & 63;
        int grow = kt * KT + rr;
        float4 v = make_float4(0.f, 0.f, 0.f, 0.f);
        if (grow < NH)
          v = *(const float4*)(W2T + (size_t)grow * W2T_STRIDE + jc * JC + (cc << 2));
        W2L[idx] = v;
      }
      __syncthreads();

      ull qA[8], qB[8];
      #pragma unroll
      for (int g = 0; g < 8; ++g) {
        int h = r * 128 + g * 16 + wid;
        if (h < tc) {
          const ull* mp = s1seg + ((size_t)h * BATCH + b) * 8 + 2 * kt;
          qA[g] = mp[0]; qB[g] = mp[1];
        } else { qA[g] = 0; qB[g] = 0; }
      }
      #pragma unroll
      for (int g = 0; g < 8; ++g) {
        ull mA = rfl64(qA[g]);
        ull mB = rfl64(qB[g]);
        PEEL4(mA, 0,  acc[g]);
        PEEL4(mB, 64, acc[g]);
      }
    }

    #pragma unroll
    for (int g = 0; g < 8; ++g) {
      int h = r * 128 + g * 16 + wid;
      if (h < tc) {
        float4 v = make_float4(acc[g].x + b2v.x, acc[g].y + b2v.y,
                               acc[g].z + b2v.z, acc[g].w + b2v.w);
        *(float4*)(cur2seg + ((size_t)h * BATCH + b) * CSTRIDE + j0) = v;
      }
    }
  }
}

// ---------------------------------------------------------------------------
// scan2_seg (teamed): m2 recurrence. grid = 128 (b), 512 thr = 8 waves.
// cur2seg staged in 32-step x 512-j LDS windows (64 KB, double-buffered);
// next window's global loads issue before the current window's scan -> HBM
// latency hides under ~1500 cy of scan. Thread j = tid; wave w = word w.
// ---------------------------------------------------------------------------
__global__ __launch_bounds__(512) void scan2_seg_kernel(
    const float* __restrict__ cur2seg, // [tc][B][512]
    float* __restrict__ m2state,       // [B][512]
    ull* __restrict__ s2seg,           // [tc][B][8]
    int t0, int tc)
{
  __shared__ float buf[2][SW][512];    // 128 KB
  const int b = blockIdx.x;
  const int tid = threadIdx.x;
  const int lane = tid & 63, wid = tid >> 6;
  const int j = tid;
  const bool jv = (j < NH);

  float m2 = (t0 == 0) ? 0.f : m2state[b * 512 + j];

  float4 stg[8];
  #define LOADWIN(w0) do {                                                    \
    int base_ = (w0) * SW;                                                    \
    _Pragma("unroll")                                                         \
    for (int q = 0; q < 8; ++q) {                                             \
      int flat_ = tid + q * 512;            /* 0..4095 float4 units */        \
      int row_ = flat_ >> 7, c4_ = flat_ & 127;                               \
      int hh_ = base_ + row_; if (hh_ > tc - 1) hh_ = tc - 1;                 \
      stg[q] = *(const float4*)(cur2seg +                                     \
               ((size_t)hh_ * BATCH + b) * CSTRIDE + (c4_ << 2));             \
    }                                                                         \
  } while (0)
  #define WRITEWIN(pb) do {                                                   \
    _Pragma("unroll")                                                         \
    for (int q = 0; q < 8; ++q) {                                             \
      int flat_ = tid + q * 512;                                              \
      int row_ = flat_ >> 7, c4_ = flat_ & 127;                               \
      *(float4*)&buf[pb][row_][c4_ << 2] = stg[q];                            \
    }                                                                         \
  } while (0)

  const int nwin = (tc + SW - 1) / SW;

  LOADWIN(0);
  WRITEWIN(0);
  __syncthreads();

  for (int wnd = 0; wnd < nwin; ++wnd) {
    if (wnd + 1 < nwin) LOADWIN(wnd + 1);      // issue early: hides HBM latency
    const int pb = wnd & 1;
    const int h0 = wnd * SW;
    #pragma unroll 4
    for (int k = 0; k < SW; ++k) {
      int h = h0 + k;
      if (h < tc) {
        float v = buf[pb][k][j];
        float rst = (m2 > THRV) ? THRV : 0.f;
        m2 = BETAV * m2 + v - rst;
        ull bm = __ballot((m2 > THRV) && jv);
        if (lane == 0) s2seg[((size_t)h * BATCH + b) * 8 + wid] = bm;
      }
    }
    __syncthreads();                           // done reading buf[pb^1] users
    if (wnd + 1 < nwin) {
      WRITEWIN(pb ^ 1);
      __syncthreads();
    }
  }
  #undef LOADWIN
  #undef WRITEWIN
  m2state[b * 512 + j] = m2;
}

// ---------------------------------------------------------------------------
// cur3_seg: cur3T[b][t] = Wout . s2[t][b] -- parallel over seg pairs.
// Transposed output layout so scan3's per-b reads are contiguous.
// ---------------------------------------------------------------------------
__global__ __launch_bounds__(256) void cur3_seg_kernel(
    const ull* __restrict__ s2seg,    // [tc][B][8]
    const float* __restrict__ Wout,   // [2][500]
    float* __restrict__ cur3T,        // [B][512] float2
    int t0, int tc)
{
  const int wid  = threadIdx.x >> 6;
  const int lane = threadIdx.x & 63;
  const int pl = blockIdx.x * 4 + wid;
  if (pl >= tc * BATCH) return;
  const int h  = pl >> 7;        // pl / BATCH
  const int bb = pl & 127;       // pl % BATCH

  float wa[NGC], wb[NGC];
  #pragma unroll
  for (int g = 0; g < NGC; ++g) {
    int j = g * 64 + lane;
    wa[g] = (j < NH) ? Wout[j] : 0.f;
    wb[g] = (j < NH) ? Wout[NH + j] : 0.f;
  }

  const ull* p = s2seg + (size_t)pl * 8;
  float c0 = 0.f, c1 = 0.f;
  #pragma unroll
  for (int g = 0; g < NGC; ++g) {
    ull mg = p[g];
    if ((mg >> lane) & 1ull) { c0 += wa[g]; c1 += wb[g]; }
  }
  #pragma unroll
  for (int off = 32; off; off >>= 1) {
    c0 += __shfl_xor(c0, off);
    c1 += __shfl_xor(c1, off);
  }
  if (lane == 0)
    *(float2*)(cur3T + ((size_t)bb * 512 + (t0 + h)) * 2) = make_float2(c0, c1);
}

// ---------------------------------------------------------------------------
// scan3: m3 recurrence, one block per batch element, 64 lanes; chunk loads
// with prefetch, serial walk via __shfl broadcast; lane k stores step k.
// ---------------------------------------------------------------------------
__global__ __launch_bounds__(64) void scan3_kernel(
    const float* __restrict__ cur3T,  // [B][512] float2
    const float* __restrict__ bout,   // [2]
    float* __restrict__ out)          // spk [T][B][2] then mem [T][B][2]
{
  const int b = blockIdx.x;
  const int lane = threadIdx.x;
  const float bo0 = bout[0], bo1 = bout[1];
  float m0 = 0.f, m1v = 0.f;

  float2 cur = *(const float2*)(cur3T + ((size_t)b * 512 + lane) * 2);

  for (int tcc = 0; tcc < T_STEPS; tcc += 64) {
    int tn = tcc + 64 + lane; if (tn > T_STEPS - 1) tn = T_STEPS - 1;
    float2 nxt = *(const float2*)(cur3T + ((size_t)b * 512 + tn) * 2);

    float c0 = cur.x + bo0, c1 = cur.y + bo1;
    int nsteps = T_STEPS - tcc; if (nsteps > 64) nsteps = 64;
    for (int k = 0; k < nsteps; ++k) {
      float cc0 = __shfl(c0, k);
      float cc1 = __shfl(c1, k);
      float r0 = (m0  > THRV) ? THRV : 0.f;
      float r1 = (m1v > THRV) ? THRV : 0.f;
      m0  = BETAV * m0  + cc0 - r0;
      m1v = BETAV * m1v + cc1 - r1;
      if (lane == k) {
        int t = tcc + k;
        size_t o = (size_t)(t * BATCH + b) * 2;
        out[o]     = (m0  > THRV) ? 1.f : 0.f;
        out[o + 1] = (m1v > THRV) ? 1.f : 0.f;
        out[(size_t)T_STEPS * BATCH * 2 + o]     = m0;
        out[(size_t)T_STEPS * BATCH * 2 + o + 1] = m1v;
      }
    }
    cur = nxt;
  }
}

extern "C" void kernel_launch(void* const* d_in, const int* in_sizes, int n_in,
                              void* d_out, int out_size, void* d_ws, size_t ws_size,
                              hipStream_t stream) {
  const float* x    = (const float*)d_in[0];
  const float* W1   = (const float*)d_in[1];
  const float* b1   = (const float*)d_in[2];
  const float* W2   = (const float*)d_in[3];
  const float* b2   = (const float*)d_in[4];
  const float* Wout = (const float*)d_in[5];
  const float* bout = (const float*)d_in[6];
  float* out = (float*)d_out;

  // ---- carve workspace (all 512-aligned) ----
  size_t off = 0;
  char* base = (char*)d_ws;
  auto carve = [&](size_t bytes) -> char* {
    char* r = base + off;
    off += (bytes + 511) & ~(size_t)511;
    return r;
  };
  float* W2T     = (float*)carve((size_t)NH * W2T_STRIDE * 4);
  float* m1state = (float*)carve((size_t)BATCH * 512 * 4);
  float* m2state = (float*)carve((size_t)BATCH * 512 * 4);
  float* cur3T   = (float*)carve((size_t)BATCH * 512 * 2 * 4);   // 512 KB

  const size_t per_t = ((size_t)BATCH * 8 * 8)        // s1seg
                     + ((size_t)BATCH * 8 * 8)        // s2seg
                     + ((size_t)BATCH * CSTRIDE * 4); // cur2seg
  long long avail = (long long)ws_size - (long long)off - 4096;
  int TSEG = (avail > 0) ? (int)(avail / (long long)per_t) : 1;
  if (TSEG > T_STEPS) TSEG = T_STEPS;
  if (TSEG < 1) TSEG = 1;

  ull*   s1seg   = (ull*)carve((size_t)TSEG * BATCH * 8 * 8);
  ull*   s2seg   = (ull*)carve((size_t)TSEG * BATCH * 8 * 8);
  float* cur2seg = (float*)carve((size_t)TSEG * BATCH * CSTRIDE * 4);

  transpose_w2<<<(NH * W2T_STRIDE + 255) / 256, 256, 0, stream>>>(W2, W2T);

  for (int t0 = 0; t0 < T_STEPS; t0 += TSEG) {
    int tc = T_STEPS - t0; if (tc > TSEG) tc = TSEG;
    s1_seg_kernel<<<dim3(BATCH, 2), 256, 0, stream>>>(x, W1, b1, m1state, s1seg, t0, tc);
    cur2_seg_kernel<<<dim3(BATCH, 2), 1024, 0, stream>>>(s1seg, W2T, b2, cur2seg, tc);
    scan2_seg_kernel<<<BATCH, 512, 0, stream>>>(cur2seg, m2state, s2seg, t0, tc);
    cur3_seg_kernel<<<(tc * BATCH + 3) / 4, 256, 0, stream>>>(s2seg, Wout, cur3T, t0, tc);
  }
  scan3_kernel<<<BATCH, 64, 0, stream>>>(cur3T, bout, out);
}

// Round 13
// 335.937 us; speedup vs baseline: 1.3004x; 1.3004x over previous
//
#include <hip/hip_runtime.h>

#define T_STEPS 500
#define BATCH   128
#define NINPUT  6
#define NH      500
#define THRV    1.0f
#define BETAV   0.5f
#define W2T_STRIDE 512
#define NGC     8      // s2 mask words per (t,b)
#define JC      256    // j-chunk width per block
#define KT      128    // W2 rows per LDS tile

typedef unsigned long long ull;

static __device__ __forceinline__ ull rfl64(ull v) {
  unsigned lo = __builtin_amdgcn_readfirstlane((unsigned)v);
  unsigned hi = __builtin_amdgcn_readfirstlane((unsigned)(v >> 32));
  return ((ull)hi << 32) | lo;
}

// ---------------------------------------------------------------------------
// Transpose W2 [500][500] -> W2T [500][512] (padded stride, pad zeroed).
// ---------------------------------------------------------------------------
__global__ void transpose_w2(const float* __restrict__ W2, float* __restrict__ W2T) {
  int idx = blockIdx.x * 256 + threadIdx.x;
  if (idx < NH * W2T_STRIDE) {
    int i = idx >> 9;
    int j = idx & 511;
    W2T[idx] = (j < NH) ? W2[j * NH + i] : 0.f;
  }
}

// ---------------------------------------------------------------------------
// fused_kernel = s1 + cur2 + scan2.  grid = (128 b, 2 jc), 1024 thr = 16 waves,
// 1 block/CU (128 KB LDS arena).
// Phase 1: waves 0-7 run the 500-step layer-1 LIF (x staged in arena tail),
//          ballot masks -> s1seg[h][b][8] (L2; both jc blocks write identical
//          values -- deterministic).
// Phase 2: 4 rounds of 128 h. Per round: 4 K-tiles of W2 staged in the arena
//          (as W2L), PEEL4 sparse accumulate (order bit-identical to r11);
//          then acc+b2 -> scan buffer SBUF (aliases W2L, protected by
//          barriers), threads 0-255 advance m2 128 steps, ballot -> s2seg.
//          m2 carried in registers across rounds. No cur2seg round-trip.
// ---------------------------------------------------------------------------
#define PEEL4(mm, roff, A) do {                                               \
  ull m_ = (mm);                                                              \
  while (m_) {                                                                \
    int i0 = __builtin_ctzll(m_); m_ &= m_ - 1;                               \
    bool v1 = (m_ != 0); int i1 = v1 ? __builtin_ctzll(m_) : i0;              \
    if (v1) m_ &= m_ - 1;                                                     \
    bool v2 = (m_ != 0); int i2 = v2 ? __builtin_ctzll(m_) : i0;              \
    if (v2) m_ &= m_ - 1;                                                     \
    bool v3 = (m_ != 0); int i3 = v3 ? __builtin_ctzll(m_) : i0;              \
    if (v3) m_ &= m_ - 1;                                                     \
    float4 w0_ = W2L[(((roff) + i0) << 6) + lane];                            \
    float4 w1_ = W2L[(((roff) + i1) << 6) + lane];                            \
    float4 w2_ = W2L[(((roff) + i2) << 6) + lane];                            \
    float4 w3_ = W2L[(((roff) + i3) << 6) + lane];                            \
    A.x += w0_.x; A.y += w0_.y; A.z += w0_.z; A.w += w0_.w;                   \
    if (v1) { A.x += w1_.x; A.y += w1_.y; A.z += w1_.z; A.w += w1_.w; }       \
    if (v2) { A.x += w2_.x; A.y += w2_.y; A.z += w2_.z; A.w += w2_.w; }       \
    if (v3) { A.x += w3_.x; A.y += w3_.y; A.z += w3_.z; A.w += w3_.w; }       \
  }                                                                           \
} while (0)

__global__ __launch_bounds__(1024, 4) void fused_kernel(
    const float* __restrict__ x,      // [T][B][6]
    const float* __restrict__ W1,     // [500][6]
    const float* __restrict__ b1,     // [500]
    const float* __restrict__ W2T,    // [500][512]
    const float* __restrict__ b2,     // [500]
    ull* __restrict__ s1seg,          // [T][B][8] scratch
    ull* __restrict__ s2seg)          // [T][B][8] out
{
  __shared__ __align__(16) char arena[131072];   // 128 KB
  float4* W2L  = (float4*)arena;                              // [128][64] f4
  float*  SBUF = (float*)arena;                               // [128][256] f
  float*  xs   = (float*)(arena + 131072 - T_STEPS * NINPUT * 4); // 12 KB tail

  const int b = blockIdx.x, jc = blockIdx.y;
  const int tid = threadIdx.x;
  const int lane = tid & 63, wid = tid >> 6;

  // ================= phase 1: layer-1 s1 masks =================
  for (int idx = tid; idx < T_STEPS * NINPUT; idx += 1024) {
    int t = idx / NINPUT, k = idx - t * NINPUT;
    xs[idx] = x[(size_t)(t * BATCH + b) * NINPUT + k];
  }
  __syncthreads();

  if (wid < 8) {
    const int n = (wid << 6) + lane;
    const bool nv = (n < NH);
    float w[6], b1v;
    #pragma unroll
    for (int k = 0; k < 6; ++k) w[k] = nv ? W1[n * NINPUT + k] : 0.f;
    b1v = nv ? b1[n] : 0.f;
    float m1 = 0.f;

    #define LOADL(hh, xr) do {                                 \
      const float* p_ = xs + (hh) * NINPUT;                    \
      float2 a_ = *(const float2*)p_;                          \
      float2 c_ = *(const float2*)(p_ + 2);                    \
      float2 d_ = *(const float2*)(p_ + 4);                    \
      xr[0]=a_.x; xr[1]=a_.y; xr[2]=c_.x;                      \
      xr[3]=c_.y; xr[4]=d_.x; xr[5]=d_.y;                      \
    } while (0)

    float X0[6], X1[6], X2[6];
    LOADL(0, X0);
    LOADL(1, X1);
    for (int h = 0; h < T_STEPS; ++h) {
      int hp = h + 2; if (hp > T_STEPS - 1) hp = T_STEPS - 1;
      LOADL(hp, X2);
      float cur = b1v + w[0]*X0[0] + w[1]*X0[1] + w[2]*X0[2]
                      + w[3]*X0[3] + w[4]*X0[4] + w[5]*X0[5];
      float rst = (m1 > THRV) ? THRV : 0.f;
      m1 = BETAV * m1 + cur - rst;
      ull bm = __ballot((m1 > THRV) && nv);
      if (lane == 0) s1seg[((size_t)h * BATCH + b) * 8 + wid] = bm;
      #pragma unroll
      for (int k = 0; k < 6; ++k) { X0[k] = X1[k]; X1[k] = X2[k]; }
    }
    #undef LOADL
  }
  __syncthreads();   // phase-1 stores drained (vmcnt before barrier)

  // ================= phase 2: cur2 accumulate + m2 scan =================
  const int j0 = jc * JC + (lane << 2);          // accumulate columns
  const bool jv4 = (j0 < NH);
  float4 b2v = make_float4(0.f, 0.f, 0.f, 0.f);
  if (jv4) b2v = *(const float4*)(b2 + j0);

  const int jg = jc * 256 + tid;                 // scan column (tid<256)
  const bool jvs = (jg < NH);
  const int word = jc * 4 + (tid >> 6);
  float m2 = 0.f;

  for (int r = 0; r < 4; ++r) {
    float4 acc[8];
    #pragma unroll
    for (int g = 0; g < 8; ++g) acc[g] = make_float4(0.f, 0.f, 0.f, 0.f);

    for (int kt = 0; kt < 4; ++kt) {
      __syncthreads();   // protects W2L/SBUF from previous readers
      for (int idx = tid; idx < KT * (JC / 4); idx += 1024) {
        int rr = idx >> 6, cc = idx & 63;
        int grow = kt * KT + rr;
        float4 v = make_float4(0.f, 0.f, 0.f, 0.f);
        if (grow < NH)
          v = *(const float4*)(W2T + (size_t)grow * W2T_STRIDE + jc * JC + (cc << 2));
        W2L[idx] = v;
      }
      __syncthreads();

      ull qA[8], qB[8];
      #pragma unroll
      for (int g = 0; g < 8; ++g) {
        int h = r * 128 + g * 16 + wid;
        if (h < T_STEPS) {
          const ull* mp = s1seg + ((size_t)h * BATCH + b) * 8 + 2 * kt;
          qA[g] = mp[0]; qB[g] = mp[1];
        } else { qA[g] = 0; qB[g] = 0; }
      }
      #pragma unroll
      for (int g = 0; g < 8; ++g) {
        ull mA = rfl64(qA[g]);
        ull mB = rfl64(qB[g]);
        PEEL4(mA, 0,  acc[g]);
        PEEL4(mB, 64, acc[g]);
      }
    }

    __syncthreads();   // all waves done reading W2L tile kt=3
    #pragma unroll
    for (int g = 0; g < 8; ++g) {
      float4 v = make_float4(acc[g].x + b2v.x, acc[g].y + b2v.y,
                             acc[g].z + b2v.z, acc[g].w + b2v.w);
      *(float4*)&SBUF[(size_t)(g * 16 + wid) * 256 + (lane << 2)] = v;
    }
    __syncthreads();

    if (tid < 256) {
      #pragma unroll 4
      for (int hl = 0; hl < 128; ++hl) {
        int h = r * 128 + hl;
        if (h < T_STEPS) {
          float v = SBUF[hl * 256 + tid];
          float rst = (m2 > THRV) ? THRV : 0.f;
          m2 = BETAV * m2 + v - rst;
          ull bm = __ballot((m2 > THRV) && jvs);
          if (lane == 0) s2seg[((size_t)h * BATCH + b) * 8 + word] = bm;
        }
      }
    }
    // next round's first tile-staging barrier protects SBUF until scan done
  }
}

// ---------------------------------------------------------------------------
// cur3_seg: cur3T[b][t] = Wout . s2[t][b] -- fully parallel over (t,b).
// Transposed output layout so scan3's per-b reads are contiguous.
// ---------------------------------------------------------------------------
__global__ __launch_bounds__(256) void cur3_seg_kernel(
    const ull* __restrict__ s2seg,    // [T][B][8]
    const float* __restrict__ Wout,   // [2][500]
    float* __restrict__ cur3T)        // [B][512] float2
{
  const int wid  = threadIdx.x >> 6;
  const int lane = threadIdx.x & 63;
  const int pl = blockIdx.x * 4 + wid;
  if (pl >= T_STEPS * BATCH) return;
  const int h  = pl >> 7;        // pl / BATCH
  const int bb = pl & 127;       // pl % BATCH

  float wa[NGC], wb[NGC];
  #pragma unroll
  for (int g = 0; g < NGC; ++g) {
    int j = g * 64 + lane;
    wa[g] = (j < NH) ? Wout[j] : 0.f;
    wb[g] = (j < NH) ? Wout[NH + j] : 0.f;
  }

  const ull* p = s2seg + (size_t)pl * 8;
  float c0 = 0.f, c1 = 0.f;
  #pragma unroll
  for (int g = 0; g < NGC; ++g) {
    ull mg = p[g];
    if ((mg >> lane) & 1ull) { c0 += wa[g]; c1 += wb[g]; }
  }
  #pragma unroll
  for (int off = 32; off; off >>= 1) {
    c0 += __shfl_xor(c0, off);
    c1 += __shfl_xor(c1, off);
  }
  if (lane == 0)
    *(float2*)(cur3T + ((size_t)bb * 512 + h) * 2) = make_float2(c0, c1);
}

// ---------------------------------------------------------------------------
// scan3: m3 recurrence, one block per batch element, 64 lanes; chunk loads
// with prefetch, serial walk via __shfl broadcast; lane k stores step k.
// ---------------------------------------------------------------------------
__global__ __launch_bounds__(64) void scan3_kernel(
    const float* __restrict__ cur3T,  // [B][512] float2
    const float* __restrict__ bout,   // [2]
    float* __restrict__ out)          // spk [T][B][2] then mem [T][B][2]
{
  const int b = blockIdx.x;
  const int lane = threadIdx.x;
  const float bo0 = bout[0], bo1 = bout[1];
  float m0 = 0.f, m1v = 0.f;

  float2 cur = *(const float2*)(cur3T + ((size_t)b * 512 + lane) * 2);

  for (int tcc = 0; tcc < T_STEPS; tcc += 64) {
    int tn = tcc + 64 + lane; if (tn > T_STEPS - 1) tn = T_STEPS - 1;
    float2 nxt = *(const float2*)(cur3T + ((size_t)b * 512 + tn) * 2);

    float c0 = cur.x + bo0, c1 = cur.y + bo1;
    int nsteps = T_STEPS - tcc; if (nsteps > 64) nsteps = 64;
    for (int k = 0; k < nsteps; ++k) {
      float cc0 = __shfl(c0, k);
      float cc1 = __shfl(c1, k);
      float r0 = (m0  > THRV) ? THRV : 0.f;
      float r1 = (m1v > THRV) ? THRV : 0.f;
      m0  = BETAV * m0  + cc0 - r0;
      m1v = BETAV * m1v + cc1 - r1;
      if (lane == k) {
        int t = tcc + k;
        size_t o = (size_t)(t * BATCH + b) * 2;
        out[o]     = (m0  > THRV) ? 1.f : 0.f;
        out[o + 1] = (m1v > THRV) ? 1.f : 0.f;
        out[(size_t)T_STEPS * BATCH * 2 + o]     = m0;
        out[(size_t)T_STEPS * BATCH * 2 + o + 1] = m1v;
      }
    }
    cur = nxt;
  }
}

extern "C" void kernel_launch(void* const* d_in, const int* in_sizes, int n_in,
                              void* d_out, int out_size, void* d_ws, size_t ws_size,
                              hipStream_t stream) {
  const float* x    = (const float*)d_in[0];
  const float* W1   = (const float*)d_in[1];
  const float* b1   = (const float*)d_in[2];
  const float* W2   = (const float*)d_in[3];
  const float* b2   = (const float*)d_in[4];
  const float* Wout = (const float*)d_in[5];
  const float* bout = (const float*)d_in[6];
  float* out = (float*)d_out;

  // ---- carve workspace (all 512-aligned); ~9.7 MB total ----
  size_t off = 0;
  char* base = (char*)d_ws;
  auto carve = [&](size_t bytes) -> char* {
    char* r = base + off;
    off += (bytes + 511) & ~(size_t)511;
    return r;
  };
  float* W2T   = (float*)carve((size_t)NH * W2T_STRIDE * 4);          // 1 MB
  ull*   s1seg = (ull*)carve((size_t)T_STEPS * BATCH * 8 * 8);        // 4 MB
  ull*   s2seg = (ull*)carve((size_t)T_STEPS * BATCH * 8 * 8);        // 4 MB
  float* cur3T = (float*)carve((size_t)BATCH * 512 * 2 * 4);          // 512 KB

  transpose_w2<<<(NH * W2T_STRIDE + 255) / 256, 256, 0, stream>>>(W2, W2T);
  fused_kernel<<<dim3(BATCH, 2), 1024, 0, stream>>>(x, W1, b1, W2T, b2, s1seg, s2seg);
  cur3_seg_kernel<<<(T_STEPS * BATCH + 3) / 4, 256, 0, stream>>>(s2seg, Wout, cur3T);
  scan3_kernel<<<BATCH, 64, 0, stream>>>(cur3T, bout, out);
}

// Round 14
// 310.981 us; speedup vs baseline: 1.4047x; 1.0802x over previous
//
#include <hip/hip_runtime.h>

#define T_STEPS 500
#define BATCH   128
#define NINPUT  6
#define NH      500
#define THRV    1.0f
#define BETAV   0.5f
#define W2T_STRIDE 512
#define NGC     8      // s2 mask words per (t,b)
#define JC      256    // j-chunk width per block
#define KT      128    // W2 rows per LDS tile

typedef unsigned long long ull;

static __device__ __forceinline__ ull rfl64(ull v) {
  unsigned lo = __builtin_amdgcn_readfirstlane((unsigned)v);
  unsigned hi = __builtin_amdgcn_readfirstlane((unsigned)(v >> 32));
  return ((ull)hi << 32) | lo;
}

// async global -> LDS, 16B per lane (dest = wave-uniform base + lane*16)
#define GLDS16(gp, lp) __builtin_amdgcn_global_load_lds(                      \
    (const __attribute__((address_space(1))) void*)(gp),                      \
    (__attribute__((address_space(3))) void*)(lp), 16, 0, 0)

// ---------------------------------------------------------------------------
// Transpose W2 [500][500] -> W2T [500][512] (padded stride, pad zeroed).
// ---------------------------------------------------------------------------
__global__ void transpose_w2(const float* __restrict__ W2, float* __restrict__ W2T) {
  int idx = blockIdx.x * 256 + threadIdx.x;
  if (idx < NH * W2T_STRIDE) {
    int i = idx >> 9;
    int j = idx & 511;
    W2T[idx] = (j < NH) ? W2[j * NH + i] : 0.f;
  }
}

// ---------------------------------------------------------------------------
// fused_kernel = s1 + cur2 + scan2.  grid = (128 b, 2 jc), 1024 thr = 16 waves,
// 1 block/CU (128 KB LDS arena).
// Phase 1: waves 0-7 run the 500-step layer-1 LIF (x staged in arena tail,
//          4-deep prefetch ring), ballot masks kept in registers and flushed
//          to s1seg every 64 steps.
// Phase 2: 4 rounds of 128 h. Per round: 4 K-tiles of W2 staged via
//          global_load_lds (no VGPR round-trip), PEEL4 sparse accumulate
//          (order bit-identical to r13); acc+b2 -> SBUF (aliases W2L),
//          threads 0-255 advance m2 128 steps, ballots batched to s2seg.
// ---------------------------------------------------------------------------
#define PEEL4(mm, roff, A) do {                                               \
  ull m_ = (mm);                                                              \
  while (m_) {                                                                \
    int i0 = __builtin_ctzll(m_); m_ &= m_ - 1;                               \
    bool v1 = (m_ != 0); int i1 = v1 ? __builtin_ctzll(m_) : i0;              \
    if (v1) m_ &= m_ - 1;                                                     \
    bool v2 = (m_ != 0); int i2 = v2 ? __builtin_ctzll(m_) : i0;              \
    if (v2) m_ &= m_ - 1;                                                     \
    bool v3 = (m_ != 0); int i3 = v3 ? __builtin_ctzll(m_) : i0;              \
    if (v3) m_ &= m_ - 1;                                                     \
    float4 w0_ = W2L[(((roff) + i0) << 6) + lane];                            \
    float4 w1_ = W2L[(((roff) + i1) << 6) + lane];                            \
    float4 w2_ = W2L[(((roff) + i2) << 6) + lane];                            \
    float4 w3_ = W2L[(((roff) + i3) << 6) + lane];                            \
    A.x += w0_.x; A.y += w0_.y; A.z += w0_.z; A.w += w0_.w;                   \
    if (v1) { A.x += w1_.x; A.y += w1_.y; A.z += w1_.z; A.w += w1_.w; }       \
    if (v2) { A.x += w2_.x; A.y += w2_.y; A.z += w2_.z; A.w += w2_.w; }       \
    if (v3) { A.x += w3_.x; A.y += w3_.y; A.z += w3_.z; A.w += w3_.w; }       \
  }                                                                           \
} while (0)

__global__ __launch_bounds__(1024, 4) void fused_kernel(
    const float* __restrict__ x,      // [T][B][6]
    const float* __restrict__ W1,     // [500][6]
    const float* __restrict__ b1,     // [500]
    const float* __restrict__ W2T,    // [500][512]
    const float* __restrict__ b2,     // [500]
    ull* __restrict__ s1seg,          // [T][B][8] scratch
    ull* __restrict__ s2seg)          // [T][B][8] out
{
  __shared__ __align__(16) char arena[131072];   // 128 KB
  float4* W2L  = (float4*)arena;                              // [128][64] f4
  float*  SBUF = (float*)arena;                               // [128][256] f
  float*  xs   = (float*)(arena + 131072 - T_STEPS * NINPUT * 4); // 12 KB tail

  const int b = blockIdx.x, jc = blockIdx.y;
  const int tid = threadIdx.x;
  const int lane = tid & 63, wid = tid >> 6;

  // ================= phase 1: layer-1 s1 masks =================
  for (int idx = tid; idx < T_STEPS * NINPUT; idx += 1024) {
    int t = idx / NINPUT, k = idx - t * NINPUT;
    xs[idx] = x[(size_t)(t * BATCH + b) * NINPUT + k];
  }
  __syncthreads();

  if (wid < 8) {
    const int n = (wid << 6) + lane;
    const bool nv = (n < NH);
    float w[6], b1v;
    #pragma unroll
    for (int k = 0; k < 6; ++k) w[k] = nv ? W1[n * NINPUT + k] : 0.f;
    b1v = nv ? b1[n] : 0.f;
    float m1 = 0.f;
    ull keep1 = 0;

    #define LOADL(hh, xr) do {                                 \
      const float* p_ = xs + (hh) * NINPUT;                    \
      float2 a_ = *(const float2*)p_;                          \
      float2 c_ = *(const float2*)(p_ + 2);                    \
      float2 d_ = *(const float2*)(p_ + 4);                    \
      xr[0]=a_.x; xr[1]=a_.y; xr[2]=c_.x;                      \
      xr[3]=c_.y; xr[4]=d_.x; xr[5]=d_.y;                      \
    } while (0)

    float X[4][6];
    LOADL(0, X[0]);
    LOADL(1, X[1]);
    LOADL(2, X[2]);
    LOADL(3, X[3]);

    for (int h = 0; h < T_STEPS; h += 4) {
      #pragma unroll
      for (int u = 0; u < 4; ++u) {
        int hh = h + u;
        if (hh < T_STEPS) {
          float cur = b1v + w[0]*X[u][0] + w[1]*X[u][1] + w[2]*X[u][2]
                          + w[3]*X[u][3] + w[4]*X[u][4] + w[5]*X[u][5];
          float rst = (m1 > THRV) ? THRV : 0.f;
          m1 = BETAV * m1 + cur - rst;
          ull bm = __ballot((m1 > THRV) && nv);
          keep1 = (lane == (hh & 63)) ? bm : keep1;
          if ((hh & 63) == 63)
            s1seg[((size_t)((hh - 63) + lane) * BATCH + b) * 8 + wid] = keep1;
          int hp = hh + 4; if (hp > T_STEPS - 1) hp = T_STEPS - 1;
          LOADL(hp, X[u]);   // refill 4 steps ahead
        }
      }
    }
    // tail: steps 448..499 (52)
    if (lane < (T_STEPS - 448))
      s1seg[((size_t)(448 + lane) * BATCH + b) * 8 + wid] = keep1;
    #undef LOADL
  }
  __syncthreads();   // phase-1 stores drained (vmcnt before barrier)

  // ================= phase 2: cur2 accumulate + m2 scan =================
  const int j0 = jc * JC + (lane << 2);          // accumulate columns
  const bool jv4 = (j0 < NH);
  float4 b2v = make_float4(0.f, 0.f, 0.f, 0.f);
  if (jv4) b2v = *(const float4*)(b2 + j0);

  const int jg = jc * 256 + tid;                 // scan column (tid<256)
  const bool jvs = (jg < NH);
  const int word = jc * 4 + (tid >> 6);
  float m2 = 0.f;
  ull keep2 = 0;

  for (int r = 0; r < 4; ++r) {
    float4 acc[8];
    #pragma unroll
    for (int g = 0; g < 8; ++g) acc[g] = make_float4(0.f, 0.f, 0.f, 0.f);

    for (int kt = 0; kt < 4; ++kt) {
      __syncthreads();   // protects W2L/SBUF from previous readers
      // stage tile kt via async global->LDS DMA (16B/lane, linear dest)
      #pragma unroll
      for (int q = 0; q < 8; ++q) {
        int flat = tid + q * 1024;          // 0..8191 float4 units
        int rr = flat >> 6, cc = flat & 63;
        int grow = kt * KT + rr;
        int growc = (grow < NH) ? grow : (NH - 1);   // clamp: rows>=NH unread
        const float* gsrc = W2T + (size_t)growc * W2T_STRIDE + jc * JC + (cc << 2);
        GLDS16(gsrc, &W2L[flat]);
      }
      __syncthreads();   // vmcnt(0) drained before barrier -> tile ready

      ull qA[8], qB[8];
      #pragma unroll
      for (int g = 0; g < 8; ++g) {
        int h = r * 128 + g * 16 + wid;
        if (h < T_STEPS) {
          const ull* mp = s1seg + ((size_t)h * BATCH + b) * 8 + 2 * kt;
          qA[g] = mp[0]; qB[g] = mp[1];
        } else { qA[g] = 0; qB[g] = 0; }
      }
      #pragma unroll
      for (int g = 0; g < 8; ++g) {
        ull mA = rfl64(qA[g]);
        ull mB = rfl64(qB[g]);
        PEEL4(mA, 0,  acc[g]);
        PEEL4(mB, 64, acc[g]);
      }
    }

    __syncthreads();   // all waves done reading W2L tile kt=3
    #pragma unroll
    for (int g = 0; g < 8; ++g) {
      float4 v = make_float4(acc[g].x + b2v.x, acc[g].y + b2v.y,
                             acc[g].z + b2v.z, acc[g].w + b2v.w);
      *(float4*)&SBUF[(size_t)(g * 16 + wid) * 256 + (lane << 2)] = v;
    }
    __syncthreads();

    if (tid < 256) {
      #pragma unroll 4
      for (int hl = 0; hl < 128; ++hl) {
        int h = r * 128 + hl;
        if (h < T_STEPS) {
          float v = SBUF[hl * 256 + tid];
          float rst = (m2 > THRV) ? THRV : 0.f;
          m2 = BETAV * m2 + v - rst;
          ull bm = __ballot((m2 > THRV) && jvs);
          keep2 = (lane == (h & 63)) ? bm : keep2;
          if ((h & 63) == 63)
            s2seg[((size_t)((h - 63) + lane) * BATCH + b) * 8 + word] = keep2;
        }
      }
    }
    // next round's first tile-staging barrier protects SBUF until scan done
  }
  // scan tail: steps 448..499 (52)
  if (tid < 256 && lane < (T_STEPS - 448))
    s2seg[((size_t)(448 + lane) * BATCH + b) * 8 + word] = keep2;
}

// ---------------------------------------------------------------------------
// cur3_seg: cur3T[b][t] = Wout . s2[t][b] -- fully parallel over (t,b).
// Transposed output layout so scan3's per-b reads are contiguous.
// ---------------------------------------------------------------------------
__global__ __launch_bounds__(256) void cur3_seg_kernel(
    const ull* __restrict__ s2seg,    // [T][B][8]
    const float* __restrict__ Wout,   // [2][500]
    float* __restrict__ cur3T)        // [B][512] float2
{
  const int wid  = threadIdx.x >> 6;
  const int lane = threadIdx.x & 63;
  const int pl = blockIdx.x * 4 + wid;
  if (pl >= T_STEPS * BATCH) return;
  const int h  = pl >> 7;        // pl / BATCH
  const int bb = pl & 127;       // pl % BATCH

  float wa[NGC], wb[NGC];
  #pragma unroll
  for (int g = 0; g < NGC; ++g) {
    int j = g * 64 + lane;
    wa[g] = (j < NH) ? Wout[j] : 0.f;
    wb[g] = (j < NH) ? Wout[NH + j] : 0.f;
  }

  const ull* p = s2seg + (size_t)pl * 8;
  float c0 = 0.f, c1 = 0.f;
  #pragma unroll
  for (int g = 0; g < NGC; ++g) {
    ull mg = p[g];
    if ((mg >> lane) & 1ull) { c0 += wa[g]; c1 += wb[g]; }
  }
  #pragma unroll
  for (int off = 32; off; off >>= 1) {
    c0 += __shfl_xor(c0, off);
    c1 += __shfl_xor(c1, off);
  }
  if (lane == 0)
    *(float2*)(cur3T + ((size_t)bb * 512 + h) * 2) = make_float2(c0, c1);
}

// ---------------------------------------------------------------------------
// scan3: m3 recurrence, one block per batch element, 64 lanes; chunk loads
// with prefetch, serial walk via __shfl broadcast; lane k stores step k.
// ---------------------------------------------------------------------------
__global__ __launch_bounds__(64) void scan3_kernel(
    const float* __restrict__ cur3T,  // [B][512] float2
    const float* __restrict__ bout,   // [2]
    float* __restrict__ out)          // spk [T][B][2] then mem [T][B][2]
{
  const int b = blockIdx.x;
  const int lane = threadIdx.x;
  const float bo0 = bout[0], bo1 = bout[1];
  float m0 = 0.f, m1v = 0.f;

  float2 cur = *(const float2*)(cur3T + ((size_t)b * 512 + lane) * 2);

  for (int tcc = 0; tcc < T_STEPS; tcc += 64) {
    int tn = tcc + 64 + lane; if (tn > T_STEPS - 1) tn = T_STEPS - 1;
    float2 nxt = *(const float2*)(cur3T + ((size_t)b * 512 + tn) * 2);

    float c0 = cur.x + bo0, c1 = cur.y + bo1;
    int nsteps = T_STEPS - tcc; if (nsteps > 64) nsteps = 64;
    for (int k = 0; k < nsteps; ++k) {
      float cc0 = __shfl(c0, k);
      float cc1 = __shfl(c1, k);
      float r0 = (m0  > THRV) ? THRV : 0.f;
      float r1 = (m1v > THRV) ? THRV : 0.f;
      m0  = BETAV * m0  + cc0 - r0;
      m1v = BETAV * m1v + cc1 - r1;
      if (lane == k) {
        int t = tcc + k;
        size_t o = (size_t)(t * BATCH + b) * 2;
        out[o]     = (m0  > THRV) ? 1.f : 0.f;
        out[o + 1] = (m1v > THRV) ? 1.f : 0.f;
        out[(size_t)T_STEPS * BATCH * 2 + o]     = m0;
        out[(size_t)T_STEPS * BATCH * 2 + o + 1] = m1v;
      }
    }
    cur = nxt;
  }
}

extern "C" void kernel_launch(void* const* d_in, const int* in_sizes, int n_in,
                              void* d_out, int out_size, void* d_ws, size_t ws_size,
                              hipStream_t stream) {
  const float* x    = (const float*)d_in[0];
  const float* W1   = (const float*)d_in[1];
  const float* b1   = (const float*)d_in[2];
  const float* W2   = (const float*)d_in[3];
  const float* b2   = (const float*)d_in[4];
  const float* Wout = (const float*)d_in[5];
  const float* bout = (const float*)d_in[6];
  float* out = (float*)d_out;

  // ---- carve workspace (all 512-aligned); ~9.7 MB total ----
  size_t off = 0;
  char* base = (char*)d_ws;
  auto carve = [&](size_t bytes) -> char* {
    char* r = base + off;
    off += (bytes + 511) & ~(size_t)511;
    return r;
  };
  float* W2T   = (float*)carve((size_t)NH * W2T_STRIDE * 4);          // 1 MB
  ull*   s1seg = (ull*)carve((size_t)T_STEPS * BATCH * 8 * 8);        // 4 MB
  ull*   s2seg = (ull*)carve((size_t)T_STEPS * BATCH * 8 * 8);        // 4 MB
  float* cur3T = (float*)carve((size_t)BATCH * 512 * 2 * 4);          // 512 KB

  transpose_w2<<<(NH * W2T_STRIDE + 255) / 256, 256, 0, stream>>>(W2, W2T);
  fused_kernel<<<dim3(BATCH, 2), 1024, 0, stream>>>(x, W1, b1, W2T, b2, s1seg, s2seg);
  cur3_seg_kernel<<<(T_STEPS * BATCH + 3) / 4, 256, 0, stream>>>(s2seg, Wout, cur3T);
  scan3_kernel<<<BATCH, 64, 0, stream>>>(cur3T, bout, out);
}